// Round 12
// baseline (672.147 us; speedup 1.0000x reference)
//
#include <hip/hip_runtime.h>
#include <hip/hip_bf16.h>
#include <stdint.h>

#define NB 8192
#define DD 1024
#define HRD 512
#define HED 4096
#define HFD 2048

typedef __attribute__((ext_vector_type(8))) short bf16x8;
typedef __attribute__((ext_vector_type(4))) float f32x4;
typedef unsigned short u16;

__device__ __forceinline__ u16 f2b(float f) {
    union { float f; uint32_t i; } c; c.f = f;
    uint32_t r = c.i + 0x7FFF + ((c.i >> 16) & 1);   // RNE
    return (u16)(r >> 16);
}
__device__ __forceinline__ float b2f(u16 u) {
    union { uint32_t i; float f; } c; c.i = ((uint32_t)u) << 16; return c.f;
}

// bijective XCD-chunk swizzle (m204). fast axis = bn so each XCD chunk covers
// FEW A-tiles x MANY B-panels -> the streamed A operand is shared through the
// XCD's private L2 (r8: L2 FETCH 274->81 MB).
__device__ __forceinline__ void xcd_swz(int flat, int nwg, int nFast, int& f, int& s) {
    int xcd = flat & 7, rest = flat >> 3;
    int q = nwg >> 3, r = nwg & 7;
    int wg = (xcd < r ? xcd * (q + 1) : r * (q + 1) + (xcd - r) * q) + rest;
    f = wg % nFast; s = wg / nFast;
}

#define GLDS(g, l) __builtin_amdgcn_global_load_lds( \
    (const __attribute__((address_space(1))) void*)(g), \
    (__attribute__((address_space(3))) void*)(l), 16, 0, 0)

// ---------------- init ----------------
__global__ void k_init(int* cnt) { if (threadIdx.x < 2) cnt[threadIdx.x] = 0; }

// ---------------- split x into bf16 hi/lo ----------------
__global__ __launch_bounds__(256) void k_split(const float4* __restrict__ x4,
                                               ushort4* __restrict__ hi4,
                                               ushort4* __restrict__ lo4) {
    int i = blockIdx.x * 256 + threadIdx.x;
    float4 v = x4[i];
    ushort4 h, l;
    h.x = f2b(v.x); l.x = f2b(v.x - b2f(h.x));
    h.y = f2b(v.y); l.y = f2b(v.y - b2f(h.y));
    h.z = f2b(v.z); l.z = f2b(v.z - b2f(h.z));
    h.w = f2b(v.w); l.w = f2b(v.w - b2f(h.w));
    hi4[i] = h; lo4[i] = l;
}

// ---------------- transpose fp32 [R][C] -> bf16 [C][R] ----------------
__global__ __launch_bounds__(256) void k_transpose(const float* __restrict__ in,
                                                   u16* __restrict__ out, int R, int C) {
    __shared__ float s[64][65];
    int tx = threadIdx.x & 63, ty = threadIdx.x >> 6;
    int c0 = blockIdx.x * 64, r0 = blockIdx.y * 64;
#pragma unroll
    for (int j = 0; j < 16; j++) { int r = ty + j * 4; s[r][tx] = in[(size_t)(r0 + r) * C + c0 + tx]; }
    __syncthreads();
#pragma unroll
    for (int j = 0; j < 16; j++) { int c = ty + j * 4; out[(size_t)(c0 + c) * R + r0 + tx] = f2b(s[tx][c]); }
}

__global__ __launch_bounds__(256) void k_transpose_split(const float* __restrict__ in,
                                                         u16* __restrict__ ohi, u16* __restrict__ olo,
                                                         int R, int C) {
    __shared__ float s[64][65];
    int tx = threadIdx.x & 63, ty = threadIdx.x >> 6;
    int c0 = blockIdx.x * 64, r0 = blockIdx.y * 64;
#pragma unroll
    for (int j = 0; j < 16; j++) { int r = ty + j * 4; s[r][tx] = in[(size_t)(r0 + r) * C + c0 + tx]; }
    __syncthreads();
#pragma unroll
    for (int j = 0; j < 16; j++) {
        int c = ty + j * 4;
        float v = s[tx][c];
        u16 h = f2b(v);
        ohi[(size_t)(c0 + c) * R + r0 + tx] = h;
        olo[(size_t)(c0 + c) * R + r0 + tx] = f2b(v - b2f(h));
    }
}

// ---------------- LDS tile staging: 128 rows x 64 bf16 (256-thread router) ----------------
__device__ __forceinline__ void stage_tile(const char* gRowBase, long rowStrideBytes,
                                           u16* s, int tid) {
    int wave = tid >> 6, lane = tid & 63;
#pragma unroll
    for (int is = 0; is < 4; ++is) {
        int c = wave * 4 + is;                 // 1KB chunk, wave-uniform
        int row = c * 8 + (lane >> 3);
        const char* g = gRowBase + (long)row * rowStrideBytes + (lane & 7) * 16;
        GLDS(g, (char*)s + c * 1024);
    }
}

// ---------------- router GEMM (128^2 tile, 2-phase dbuf) ----------------
__global__ __launch_bounds__(256) void k_router(const u16* __restrict__ Ah, const u16* __restrict__ Al,
                                                const u16* __restrict__ Bh, const u16* __restrict__ Bl,
                                                const float* __restrict__ bias, float* __restrict__ H) {
    __shared__ u16 sAh[2][128 * 64], sAl[2][128 * 64], sBh[2][128 * 64], sBl[2][128 * 64];
    int tid = threadIdx.x, lane = tid & 63, wave = tid >> 6;
    int flat = blockIdx.y * gridDim.x + blockIdx.x;
    int bm, bn;
    xcd_swz(flat, gridDim.x * gridDim.y, gridDim.y, bn, bm);   // bn fast
    f32x4 acc[4][4];
#pragma unroll
    for (int i = 0; i < 4; i++)
#pragma unroll
        for (int j = 0; j < 4; j++) acc[i][j] = (f32x4)0.f;
    int wm = (wave & 1) * 64, wn = (wave >> 1) * 64;
    const char* ahBase = (const char*)(Ah + (size_t)bm * 128 * DD);
    const char* alBase = (const char*)(Al + (size_t)bm * 128 * DD);
    const char* bhBase = (const char*)(Bh + (size_t)bn * 128 * DD);
    const char* blBase = (const char*)(Bl + (size_t)bn * 128 * DD);
    const int nk = DD / 64;
    stage_tile(ahBase, DD * 2, sAh[0], tid);
    stage_tile(alBase, DD * 2, sAl[0], tid);
    stage_tile(bhBase, DD * 2, sBh[0], tid);
    stage_tile(blBase, DD * 2, sBl[0], tid);
    asm volatile("s_waitcnt vmcnt(0)" ::: "memory");
    __builtin_amdgcn_s_barrier();
    int cur = 0;
    for (int it = 0; it < nk; ++it) {
        if (it + 1 < nk) {
            size_t ofs = (size_t)(it + 1) * 128;
            stage_tile(ahBase + ofs, DD * 2, sAh[cur ^ 1], tid);
            stage_tile(alBase + ofs, DD * 2, sAl[cur ^ 1], tid);
            stage_tile(bhBase + ofs, DD * 2, sBh[cur ^ 1], tid);
            stage_tile(blBase + ofs, DD * 2, sBl[cur ^ 1], tid);
        }
        const u16* pAh = sAh[cur]; const u16* pAl = sAl[cur];
        const u16* pBh = sBh[cur]; const u16* pBl = sBl[cur];
#pragma unroll
        for (int kk = 0; kk < 2; kk++) {
            int kofs = kk * 64 + (lane >> 4) * 16;
            bf16x8 vbh[4], vbl[4];
#pragma unroll
            for (int ni = 0; ni < 4; ni++) {
                int rB = (wn + ni * 16 + (lane & 15)) * 128 + kofs;
                vbh[ni] = *(const bf16x8*)((const char*)pBh + rB);
                vbl[ni] = *(const bf16x8*)((const char*)pBl + rB);
            }
#pragma unroll
            for (int mi = 0; mi < 4; mi++) {
                int rA = (wm + mi * 16 + (lane & 15)) * 128 + kofs;
                bf16x8 vah = *(const bf16x8*)((const char*)pAh + rA);
                bf16x8 val = *(const bf16x8*)((const char*)pAl + rA);
#pragma unroll
                for (int ni = 0; ni < 4; ni++) {
                    acc[mi][ni] = __builtin_amdgcn_mfma_f32_16x16x32_bf16(vah, vbh[ni], acc[mi][ni], 0, 0, 0);
                    acc[mi][ni] = __builtin_amdgcn_mfma_f32_16x16x32_bf16(vah, vbl[ni], acc[mi][ni], 0, 0, 0);
                    acc[mi][ni] = __builtin_amdgcn_mfma_f32_16x16x32_bf16(val, vbh[ni], acc[mi][ni], 0, 0, 0);
                }
            }
        }
        asm volatile("s_waitcnt vmcnt(0)" ::: "memory");
        __builtin_amdgcn_s_barrier();
        cur ^= 1;
    }
    int quad = lane >> 4, cl = lane & 15;
#pragma unroll
    for (int mi = 0; mi < 4; mi++)
#pragma unroll
        for (int r = 0; r < 4; r++) {
            int row = bm * 128 + wm + mi * 16 + quad * 4 + r;
#pragma unroll
            for (int ni = 0; ni < 4; ni++) {
                int col = bn * 128 + wn + ni * 16 + cl;
                float v = acc[mi][ni][r] + bias[col];
                H[(size_t)row * HRD + col] = fmaxf(v, 0.f);
            }
        }
}

// ---------------- router heads ----------------
__global__ __launch_bounds__(256) void k_heads(const float* __restrict__ H,
                                               const float* __restrict__ Wd, const float* __restrict__ bd,
                                               const float* __restrict__ Wm, const float* __restrict__ Wl,
                                               int* __restrict__ cnt, int* __restrict__ perm,
                                               float* __restrict__ wsc, int* __restrict__ eic) {
    int lane = threadIdx.x & 63, wave = threadIdx.x >> 6;
    int r = blockIdx.x * 4 + wave;
    const float4* h4 = (const float4*)(H + (size_t)r * HRD);
    float4 v0 = h4[lane * 2], v1 = h4[lane * 2 + 1];
    float hv[8] = {v0.x, v0.y, v0.z, v0.w, v1.x, v1.y, v1.z, v1.w};
    float a[10];
#pragma unroll
    for (int t = 0; t < 10; t++) a[t] = 0.f;
    int kbase = lane * 8;
#pragma unroll
    for (int j = 0; j < 8; j++) {
        int k = kbase + j;
        float h_ = hv[j];
        float2 wd = ((const float2*)Wd)[k];
        a[0] += h_ * wd.x; a[1] += h_ * wd.y;
        float4 wm = ((const float4*)Wm)[k];
        a[2] += h_ * wm.x; a[3] += h_ * wm.y; a[4] += h_ * wm.z; a[5] += h_ * wm.w;
        float4 wl = ((const float4*)Wl)[k];
        a[6] += h_ * wl.x; a[7] += h_ * wl.y; a[8] += h_ * wl.z; a[9] += h_ * wl.w;
    }
#pragma unroll
    for (int t = 0; t < 10; t++)
#pragma unroll
        for (int off = 32; off > 0; off >>= 1) a[t] += __shfl_down(a[t], off);
    if (lane == 0) {
        float d0 = a[0] + bd[0], d1 = a[1] + bd[1];
        int primary = (d1 > d0) ? 1 : 0;                       // first-max tie-break
        float w = 1.f / (1.f + expf(-fabsf(d0 - d1)));         // softmax weight of chosen
        int mi = 0; float mv = a[2];
        if (a[3] > mv) { mv = a[3]; mi = 1; }
        if (a[4] > mv) { mv = a[4]; mi = 2; }
        if (a[5] > mv) { mv = a[5]; mi = 3; }
        int li = 0; float lv = a[6];
        if (a[7] > lv) { lv = a[7]; li = 1; }
        if (a[8] > lv) { lv = a[8]; li = 2; }
        int pos;
        if (a[9] > lv) { lv = a[9]; li = 3; }
        if (primary == 0) pos = atomicAdd(&cnt[0], 1);
        else              pos = NB - 1 - atomicAdd(&cnt[1], 1);
        perm[pos] = r; wsc[pos] = w; eic[pos] = (primary == 0) ? mi : li;
    }
}

// ---------------- gather ----------------
__global__ __launch_bounds__(256) void k_gather(const float* __restrict__ x,
                                                const float* __restrict__ op_emb,
                                                const float* __restrict__ task_emb,
                                                const int* __restrict__ perm, const int* __restrict__ eic,
                                                const int* __restrict__ cnt, u16* __restrict__ xin) {
    int lane = threadIdx.x & 63, wave = threadIdx.x >> 6;
    int i = blockIdx.x * 4 + wave;
    int n0 = cnt[0];
    int r = perm[i];
    const float* emb = ((i >= n0) ? task_emb : op_emb) + (size_t)eic[i] * DD;
    const float4* x4 = (const float4*)(x + (size_t)r * DD);
    const float4* e4 = (const float4*)emb;
    ushort4* o4 = (ushort4*)(xin + (size_t)i * DD);
#pragma unroll
    for (int j = 0; j < 4; j++) {
        int idx = lane + j * 64;
        float4 xv = x4[idx], ev = e4[idx];
        ushort4 o;
        o.x = f2b(xv.x + ev.x); o.y = f2b(xv.y + ev.y);
        o.z = f2b(xv.z + ev.z); o.w = f2b(xv.w + ev.w);
        o4[idx] = o;
    }
}

// ======== 256^2-tile staggered 4-phase GEMM for L1 / F1 (r11 passing) ========
template <bool DUAL>
__global__ __launch_bounds__(512) void k_g256(
    const u16* __restrict__ A, const u16* __restrict__ B0w, const u16* __restrict__ B1w,
    const float* __restrict__ bias0, const float* __restrict__ bias1,
    u16* __restrict__ Out, int K, int N, const int* __restrict__ cnt) {
    __shared__ __align__(16) u16 sA[2][256 * 64];
    __shared__ __align__(16) u16 sB[2][256 * 64];
    const int tid = threadIdx.x, lane = tid & 63, wave = tid >> 6;
    int flat = blockIdx.y * gridDim.x + blockIdx.x;
    int t, bn;
    xcd_swz(flat, gridDim.x * gridDim.y, gridDim.y, bn, t);   // bn fast

    int tile = t, storeLo = 0, storeHi = 0x7fffffff;
    const u16* Bt = B0w; const float* bias = bias0;
    if constexpr (DUAL) {
        int n0 = cnt[0];
        int tb = n0 >> 8;
        bool isMath = (t <= tb) && (t < NB / 256);
        tile = isMath ? t : (t - 1);
        if (isMath) { storeLo = tile * 256; storeHi = n0 < storeLo + 256 ? n0 : storeLo + 256; }
        else        { storeHi = tile * 256 + 256; storeLo = n0 > tile * 256 ? n0 : tile * 256;
                      Bt = B1w; bias = bias1; }
        if (storeLo >= storeHi) return;   // block-uniform, before any barrier
    }

    f32x4 acc[8][4];
#pragma unroll
    for (int i = 0; i < 8; i++)
#pragma unroll
        for (int j = 0; j < 4; j++) acc[i][j] = (f32x4)0.f;

    const int wm = (wave & 1) * 128;
    const int wn = (wave >> 1) * 64;
    const int rl = lane & 15, q = lane >> 4, x7 = lane & 7;
    const int aRow = (wave & 1) * 64;
    const int bRow = (wave >> 1) * 32;

    const long stride = (long)K * 2;
    const char* aBase = (const char*)A + (size_t)tile * 256 * stride;
    const char* bBase = (const char*)Bt + (size_t)bn * 256 * stride;
    const long srcOfs = (long)((lane & 7) ^ (lane >> 3)) << 4;
    const int waveOfs = wave * 1024;
    const int l8 = lane >> 3;

    auto SH_A = [&](int h, int kt, int d) {
        long kofs = (long)kt * 128 + srcOfs;
#pragma unroll
        for (int i = 0; i < 2; i++) {
            int gr = wave * 8 + l8 + h * 64 + i * 128;
            GLDS(aBase + (long)gr * stride + kofs,
                 (char*)&sA[d][0] + h * 16384 + i * 8192 + waveOfs);
        }
    };
    auto SH_B = [&](int h, int kt, int d) {
        long kofs = (long)kt * 128 + srcOfs;
#pragma unroll
        for (int i = 0; i < 2; i++) {
            int rp = i * 64 + wave * 8 + l8;
            int gn = (rp & 31) + ((rp >> 5) << 6) + h * 32;
            GLDS(bBase + (long)gn * stride + kofs,
                 (char*)&sB[d][0] + h * 16384 + i * 8192 + waveOfs);
        }
    };

    const int nk = K >> 6;
    SH_A(0, 0, 0); SH_B(0, 0, 0); SH_B(1, 0, 0); SH_A(1, 0, 0);
    if (nk > 1) {
        SH_A(0, 1, 1); SH_B(0, 1, 1); SH_B(1, 1, 1);
        asm volatile("s_waitcnt vmcnt(6)" ::: "memory");
    } else {
        asm volatile("s_waitcnt vmcnt(0)" ::: "memory");
    }
    __builtin_amdgcn_s_barrier();

    bf16x8 va[4][2], vb0[2][2], vb1[2][2];
    for (int kt = 0; kt < nk; ++kt) {
        const int cur = kt & 1;
        const char* pA = (const char*)&sA[cur][0];
        const char* pB = (const char*)&sB[cur][0];
        // P0
#pragma unroll
        for (int f = 0; f < 4; f++)
#pragma unroll
            for (int kk = 0; kk < 2; kk++)
                va[f][kk] = *(const bf16x8*)(pA + (aRow + f * 16 + rl) * 128 + (((kk * 4 + q) ^ x7) << 4));
#pragma unroll
        for (int g = 0; g < 2; g++)
#pragma unroll
            for (int kk = 0; kk < 2; kk++)
                vb0[g][kk] = *(const bf16x8*)(pB + (bRow + g * 16 + rl) * 128 + (((kk * 4 + q) ^ x7) << 4));
        if (kt + 1 < nk) SH_A(1, kt + 1, cur ^ 1);
        __builtin_amdgcn_s_setprio(1);
#pragma unroll
        for (int f = 0; f < 4; f++)
#pragma unroll
            for (int g = 0; g < 2; g++)
#pragma unroll
                for (int kk = 0; kk < 2; kk++)
                    acc[f][g] = __builtin_amdgcn_mfma_f32_16x16x32_bf16(va[f][kk], vb0[g][kk], acc[f][g], 0, 0, 0);
        __builtin_amdgcn_s_setprio(0);
        asm volatile("" ::: "memory");
        __builtin_amdgcn_s_barrier();
        // P1
#pragma unroll
        for (int g = 0; g < 2; g++)
#pragma unroll
            for (int kk = 0; kk < 2; kk++)
                vb1[g][kk] = *(const bf16x8*)(pB + (bRow + 128 + g * 16 + rl) * 128 + (((kk * 4 + q) ^ x7) << 4));
        if (kt + 2 < nk) SH_B(0, kt + 2, cur);
        __builtin_amdgcn_s_setprio(1);
#pragma unroll
        for (int f = 0; f < 4; f++)
#pragma unroll
            for (int g = 0; g < 2; g++)
#pragma unroll
                for (int kk = 0; kk < 2; kk++)
                    acc[f][2 + g] = __builtin_amdgcn_mfma_f32_16x16x32_bf16(va[f][kk], vb1[g][kk], acc[f][2 + g], 0, 0, 0);
        __builtin_amdgcn_s_setprio(0);
        asm volatile("" ::: "memory");
        __builtin_amdgcn_s_barrier();
        // P2
#pragma unroll
        for (int f = 0; f < 4; f++)
#pragma unroll
            for (int kk = 0; kk < 2; kk++)
                va[f][kk] = *(const bf16x8*)(pA + (aRow + 128 + f * 16 + rl) * 128 + (((kk * 4 + q) ^ x7) << 4));
        if (kt + 2 < nk) SH_B(1, kt + 2, cur);
        __builtin_amdgcn_s_setprio(1);
#pragma unroll
        for (int f = 0; f < 4; f++)
#pragma unroll
            for (int g = 0; g < 2; g++)
#pragma unroll
                for (int kk = 0; kk < 2; kk++)
                    acc[4 + f][2 + g] = __builtin_amdgcn_mfma_f32_16x16x32_bf16(va[f][kk], vb1[g][kk], acc[4 + f][2 + g], 0, 0, 0);
        __builtin_amdgcn_s_setprio(0);
        asm volatile("" ::: "memory");
        __builtin_amdgcn_s_barrier();
        // P3
        if (kt + 2 < nk) {
            SH_A(0, kt + 2, cur);
            asm volatile("s_waitcnt vmcnt(6)" ::: "memory");
        } else {
            asm volatile("s_waitcnt vmcnt(0)" ::: "memory");
        }
        __builtin_amdgcn_s_setprio(1);
#pragma unroll
        for (int f = 0; f < 4; f++)
#pragma unroll
            for (int g = 0; g < 2; g++)
#pragma unroll
                for (int kk = 0; kk < 2; kk++)
                    acc[4 + f][g] = __builtin_amdgcn_mfma_f32_16x16x32_bf16(va[f][kk], vb0[g][kk], acc[4 + f][g], 0, 0, 0);
        __builtin_amdgcn_s_setprio(0);
        asm volatile("" ::: "memory");
        __builtin_amdgcn_s_barrier();
    }

    const int quad = lane >> 4, cl = lane & 15;
#pragma unroll
    for (int f = 0; f < 8; f++)
#pragma unroll
        for (int rr = 0; rr < 4; rr++) {
            int grow = tile * 256 + wm + ((f & 3) * 16) + ((f >> 2) * 64) + quad * 4 + rr;
            if constexpr (DUAL) { if (grow < storeLo || grow >= storeHi) continue; }
#pragma unroll
            for (int g = 0; g < 4; g++) {
                int col = bn * 256 + wn + ((g & 1) * 16) + ((g >> 1) * 32) + cl;
                float v = acc[f][g][rr] + bias[col];
                Out[(size_t)grow * N + col] = f2b(fmaxf(v, 0.f));
            }
        }
}

// ======== 256x128-tile staggered 4-phase GEMM for L2 / F2 ========
// Same schedule class as k_g256 (r11 passing), B-units halved.
// 8 waves (2M x 4N), per-wave 128x32, acc[8][2]. LDS 96 KB dbuf-2.
// Units: A_L/A_H = 128-row units (2 GLDS/thr); B_L = global cols bit4-clear
// (64 lds rows, 1 GLDS/thr), B_H = bit4-set. col<->lds-row: rp = (col&15) +
// ((col>>5)<<4); reader wave w'=wave>>1 reads vb0 at row w'*16+rl (B_L),
// vb1 at 64 + w'*16 + rl (B_H). rp&7 == rl&7 -> swizzle keys consistent.
// Stagger: A_H(t+1)@P0 -> B_L(t+2)@P1 -> B_H(t+2)@P2 -> A_L(t+2)@P3 + vmcnt(4)
// (= {B_L,B_H,A_L}(t+2) = 1+1+2 loads in flight; induction as k_g256).
// EPI 1: *wsel -> bf16. EPI 2: +resid, scatter fp32 via perm.
template <int EPI, bool DUAL>
__global__ __launch_bounds__(512) void k_gSTAG(
    const u16* __restrict__ A, const u16* __restrict__ B0, const u16* __restrict__ B1,
    const float* __restrict__ bias0, const float* __restrict__ bias1,
    void* __restrict__ Out, int K, int N,
    const int* __restrict__ cnt, const float* __restrict__ wsel,
    const int* __restrict__ perm, const u16* __restrict__ resid) {
    __shared__ __align__(16) u16 sA[2][256 * 64];   // 64 KB
    __shared__ __align__(16) u16 sB[2][128 * 64];   // 32 KB
    const int tid = threadIdx.x, lane = tid & 63, wave = tid >> 6;
    int flat = blockIdx.y * gridDim.x + blockIdx.x;
    int t, bn;
    xcd_swz(flat, gridDim.x * gridDim.y, gridDim.y, bn, t);   // bn fast

    int tile = t, storeLo = 0, storeHi = 0x7fffffff;
    const u16* Bt = B0; const float* bias = bias0;
    if constexpr (DUAL) {
        int n0 = cnt[0];
        int tb = n0 >> 8;
        bool isMath = (t <= tb) && (t < NB / 256);
        tile = isMath ? t : (t - 1);
        if (isMath) { storeLo = tile * 256; storeHi = n0 < storeLo + 256 ? n0 : storeLo + 256; }
        else        { storeHi = tile * 256 + 256; storeLo = n0 > tile * 256 ? n0 : tile * 256;
                      Bt = B1; bias = bias1; }
        if (storeLo >= storeHi) return;   // block-uniform, before any barrier
    }

    f32x4 acc[8][2];
#pragma unroll
    for (int i = 0; i < 8; i++)
#pragma unroll
        for (int j = 0; j < 2; j++) acc[i][j] = (f32x4)0.f;

    const int wm = (wave & 1) * 128;       // global M base
    const int wn = (wave >> 1) * 32;       // global N base
    const int rl = lane & 15, q = lane >> 4, x7 = lane & 7;
    const int aRow = (wave & 1) * 64;      // lds-row base within an A unit
    const int bRow = (wave >> 1) * 16;     // lds-row base within a B unit

    const long stride = (long)K * 2;
    const char* aBase = (const char*)A + (size_t)tile * 256 * stride;
    const char* bBase = (const char*)Bt + (size_t)bn * 128 * stride;
    const long srcOfs = (long)((lane & 7) ^ (lane >> 3)) << 4;
    const int waveOfs = wave * 1024;
    const int l8 = lane >> 3;

    // A unit h (0=A_L: rows {0..63 U 128..191}, 1=A_H): 2 GLDS/thread
    auto SH_A = [&](int h, int kt, int d) {
        long kofs = (long)kt * 128 + srcOfs;
#pragma unroll
        for (int i = 0; i < 2; i++) {
            int gr = wave * 8 + l8 + h * 64 + i * 128;
            GLDS(aBase + (long)gr * stride + kofs,
                 (char*)&sA[d][0] + h * 16384 + i * 8192 + waveOfs);
        }
    };
    // B unit h (0=B_L cols bit4-clear, 1=B_H): 1 GLDS/thread, 64 lds rows
    auto SH_B = [&](int h, int kt, int d) {
        long kofs = (long)kt * 128 + srcOfs;
        int rp = wave * 8 + l8;                          // lds row within unit, 0..63
        int gn = (rp & 15) + ((rp >> 4) << 5) + h * 16;  // global col
        GLDS(bBase + (long)gn * stride + kofs,
             (char*)&sB[d][0] + h * 8192 + waveOfs);
    };

    const int nk = K >> 6;
    // prologue: tile0 {A_L,B_L,B_H,A_H}(6) + tile1 {A_L,B_L,B_H}(4); vmcnt(4) -> tile0 landed
    SH_A(0, 0, 0); SH_B(0, 0, 0); SH_B(1, 0, 0); SH_A(1, 0, 0);
    if (nk > 1) {
        SH_A(0, 1, 1); SH_B(0, 1, 1); SH_B(1, 1, 1);
        asm volatile("s_waitcnt vmcnt(4)" ::: "memory");
    } else {
        asm volatile("s_waitcnt vmcnt(0)" ::: "memory");
    }
    __builtin_amdgcn_s_barrier();

    bf16x8 va[4][2], vb0[2], vb1[2];
    for (int kt = 0; kt < nk; ++kt) {
        const int cur = kt & 1;
        const char* pA = (const char*)&sA[cur][0];
        const char* pB = (const char*)&sB[cur][0];
        // ---------- P0: acc[0..3][0]; stage A_H(kt+1) -> other slot ----------
#pragma unroll
        for (int f = 0; f < 4; f++)
#pragma unroll
            for (int kk = 0; kk < 2; kk++)
                va[f][kk] = *(const bf16x8*)(pA + (aRow + f * 16 + rl) * 128 + (((kk * 4 + q) ^ x7) << 4));
#pragma unroll
        for (int kk = 0; kk < 2; kk++)
            vb0[kk] = *(const bf16x8*)(pB + (bRow + rl) * 128 + (((kk * 4 + q) ^ x7) << 4));
        if (kt + 1 < nk) SH_A(1, kt + 1, cur ^ 1);
        __builtin_amdgcn_s_setprio(1);
#pragma unroll
        for (int f = 0; f < 4; f++)
#pragma unroll
            for (int kk = 0; kk < 2; kk++)
                acc[f][0] = __builtin_amdgcn_mfma_f32_16x16x32_bf16(va[f][kk], vb0[kk], acc[f][0], 0, 0, 0);
        __builtin_amdgcn_s_setprio(0);
        asm volatile("" ::: "memory");
        __builtin_amdgcn_s_barrier();
        // ---------- P1: acc[0..3][1]; stage B_L(kt+2) -> cur slot ----------
#pragma unroll
        for (int kk = 0; kk < 2; kk++)
            vb1[kk] = *(const bf16x8*)(pB + (64 + bRow + rl) * 128 + (((kk * 4 + q) ^ x7) << 4));
        if (kt + 2 < nk) SH_B(0, kt + 2, cur);
        __builtin_amdgcn_s_setprio(1);
#pragma unroll
        for (int f = 0; f < 4; f++)
#pragma unroll
            for (int kk = 0; kk < 2; kk++)
                acc[f][1] = __builtin_amdgcn_mfma_f32_16x16x32_bf16(va[f][kk], vb1[kk], acc[f][1], 0, 0, 0);
        __builtin_amdgcn_s_setprio(0);
        asm volatile("" ::: "memory");
        __builtin_amdgcn_s_barrier();
        // ---------- P2: acc[4..7][1]; stage B_H(kt+2) -> cur slot ----------
#pragma unroll
        for (int f = 0; f < 4; f++)
#pragma unroll
            for (int kk = 0; kk < 2; kk++)
                va[f][kk] = *(const bf16x8*)(pA + (aRow + 128 + f * 16 + rl) * 128 + (((kk * 4 + q) ^ x7) << 4));
        if (kt + 2 < nk) SH_B(1, kt + 2, cur);
        __builtin_amdgcn_s_setprio(1);
#pragma unroll
        for (int f = 0; f < 4; f++)
#pragma unroll
            for (int kk = 0; kk < 2; kk++)
                acc[4 + f][1] = __builtin_amdgcn_mfma_f32_16x16x32_bf16(va[f][kk], vb1[kk], acc[4 + f][1], 0, 0, 0);
        __builtin_amdgcn_s_setprio(0);
        asm volatile("" ::: "memory");
        __builtin_amdgcn_s_barrier();
        // ---------- P3: acc[4..7][0]; stage A_L(kt+2) -> cur slot; counted wait ----------
        if (kt + 2 < nk) {
            SH_A(0, kt + 2, cur);
            asm volatile("s_waitcnt vmcnt(4)" ::: "memory");   // tile kt+1 fully landed
        } else {
            asm volatile("s_waitcnt vmcnt(0)" ::: "memory");
        }
        __builtin_amdgcn_s_setprio(1);
#pragma unroll
        for (int f = 0; f < 4; f++)
#pragma unroll
            for (int kk = 0; kk < 2; kk++)
                acc[4 + f][0] = __builtin_amdgcn_mfma_f32_16x16x32_bf16(va[f][kk], vb0[kk], acc[4 + f][0], 0, 0, 0);
        __builtin_amdgcn_s_setprio(0);
        asm volatile("" ::: "memory");
        __builtin_amdgcn_s_barrier();
    }

    const int quad = lane >> 4, cl = lane & 15;
#pragma unroll
    for (int f = 0; f < 8; f++)
#pragma unroll
        for (int rr = 0; rr < 4; rr++) {
            int grow = tile * 256 + wm + ((f & 3) * 16) + ((f >> 2) * 64) + quad * 4 + rr;
            if constexpr (DUAL) { if (grow < storeLo || grow >= storeHi) continue; }
#pragma unroll
            for (int g = 0; g < 2; g++) {
                int col = bn * 128 + wn + g * 16 + cl;
                float v = acc[f][g][rr] + bias[col];
                if constexpr (EPI == 1) {
                    ((u16*)Out)[(size_t)grow * N + col] = f2b(v * wsel[grow]);
                } else {
                    v += b2f(resid[(size_t)grow * N + col]);
                    ((float*)Out)[(size_t)perm[grow] * N + col] = v;
                }
            }
        }
}

extern "C" void kernel_launch(void* const* d_in, const int* in_sizes, int n_in,
                              void* d_out, int out_size, void* d_ws, size_t ws_size,
                              hipStream_t stream) {
    const float* x      = (const float*)d_in[0];
    const float* W_r1   = (const float*)d_in[1];
    const float* b_r1   = (const float*)d_in[2];
    const float* W_dom  = (const float*)d_in[3];
    const float* b_dom  = (const float*)d_in[4];
    const float* W_mop  = (const float*)d_in[5];
    const float* W_lt   = (const float*)d_in[6];
    const float* op_emb = (const float*)d_in[7];
    const float* W_m1   = (const float*)d_in[8];
    const float* b_m1   = (const float*)d_in[9];
    const float* W_m2   = (const float*)d_in[10];
    const float* b_m2   = (const float*)d_in[11];
    const float* task_emb = (const float*)d_in[12];
    const float* W_l1   = (const float*)d_in[13];
    const float* b_l1   = (const float*)d_in[14];
    const float* W_l2   = (const float*)d_in[15];
    const float* b_l2   = (const float*)d_in[16];
    const float* W_f1   = (const float*)d_in[17];
    const float* b_f1   = (const float*)d_in[18];
    const float* W_f2   = (const float*)d_in[19];
    const float* b_f2   = (const float*)d_in[20];

    char* wsp = (char*)d_ws;
    size_t off = 0;
    auto take = [&](size_t bytes) -> char* {
        char* p = wsp + off;
        off += (bytes + 255) & ~(size_t)255;
        return p;
    };
    u16* Wr_hi = (u16*)take((size_t)HRD * DD * 2);
    u16* Wr_lo = (u16*)take((size_t)HRD * DD * 2);
    u16* Wm1t  = (u16*)take((size_t)HED * DD * 2);
    u16* Wl1t  = (u16*)take((size_t)HED * DD * 2);
    u16* Wm2t  = (u16*)take((size_t)DD * HED * 2);
    u16* Wl2t  = (u16*)take((size_t)DD * HED * 2);
    u16* Wf1t  = (u16*)take((size_t)HFD * DD * 2);
    u16* Wf2t  = (u16*)take((size_t)DD * HFD * 2);
    u16* x_hi  = (u16*)take((size_t)NB * DD * 2);
    u16* x_lo  = (u16*)take((size_t)NB * DD * 2);
    float* Hbuf = (float*)take((size_t)NB * HRD * 4);
    u16* hid   = (u16*)take((size_t)NB * HED * 2);
    int* cnt   = (int*)take(256);
    int* perm  = (int*)take(NB * 4);
    int* eic   = (int*)take(NB * 4);
    float* wsc = (float*)take(NB * 4);
    // aliases (lifetime-disjoint):
    u16* xin   = x_hi;   // gather runs after router GEMM consumed x_hi
    u16* fused = x_lo;   // L2 writes after router GEMM consumed x_lo
    u16* hid2  = Wm1t;   // F1 writes after all expert GEMMs consumed Wm1t..Wl2t (32MB contiguous)

    k_init<<<1, 64, 0, stream>>>(cnt);
    k_split<<<(NB * DD / 4) / 256, 256, 0, stream>>>((const float4*)x, (ushort4*)x_hi, (ushort4*)x_lo);
    k_transpose_split<<<dim3(HRD / 64, DD / 64), 256, 0, stream>>>(W_r1, Wr_hi, Wr_lo, DD, HRD);
    k_transpose<<<dim3(HED / 64, DD / 64), 256, 0, stream>>>(W_m1, Wm1t, DD, HED);
    k_transpose<<<dim3(HED / 64, DD / 64), 256, 0, stream>>>(W_l1, Wl1t, DD, HED);
    k_transpose<<<dim3(DD / 64, HED / 64), 256, 0, stream>>>(W_m2, Wm2t, HED, DD);
    k_transpose<<<dim3(DD / 64, HED / 64), 256, 0, stream>>>(W_l2, Wl2t, HED, DD);
    k_transpose<<<dim3(HFD / 64, DD / 64), 256, 0, stream>>>(W_f1, Wf1t, DD, HFD);
    k_transpose<<<dim3(DD / 64, HFD / 64), 256, 0, stream>>>(W_f2, Wf2t, HFD, DD);

    k_router<<<dim3(NB / 128, HRD / 128), 256, 0, stream>>>(x_hi, x_lo, Wr_hi, Wr_lo, b_r1, Hbuf);
    k_heads<<<NB / 4, 256, 0, stream>>>(Hbuf, W_dom, b_dom, W_mop, W_lt, cnt, perm, wsc, eic);
    k_gather<<<NB / 4, 256, 0, stream>>>(x, op_emb, task_emb, perm, eic, cnt, xin);

    // L1: 256^2-tile staggered 4-phase, grid (33,16)=528 blocks
    k_g256<true><<<dim3(NB / 256 + 1, HED / 256), 512, 0, stream>>>(
        xin, Wm1t, Wl1t, b_m1, b_l1, hid, DD, HED, cnt);
    // L2: 256x128 staggered 4-phase, grid (33,8)=264 blocks
    k_gSTAG<1, true><<<dim3(NB / 256 + 1, DD / 128), 512, 0, stream>>>(
        hid, Wm2t, Wl2t, b_m2, b_l2, fused, HED, DD, cnt, wsc, nullptr, nullptr);
    // F1: 256^2-tile staggered 4-phase, grid (32,8)=256 blocks
    k_g256<false><<<dim3(NB / 256, HFD / 256), 512, 0, stream>>>(
        fused, Wf1t, nullptr, b_f1, nullptr, hid2, DD, HFD, cnt);
    // F2: 256x128 staggered 4-phase, grid (32,8)=256 blocks
    k_gSTAG<2, false><<<dim3(NB / 256, DD / 128), 512, 0, stream>>>(
        hid2, Wf2t, nullptr, b_f2, nullptr, d_out, HFD, DD, cnt, nullptr, perm, fused);
}

// Round 13
// 641.258 us; speedup vs baseline: 1.0482x; 1.0482x over previous
//
#include <hip/hip_runtime.h>
#include <hip/hip_bf16.h>
#include <stdint.h>

#define NB 8192
#define DD 1024
#define HRD 512
#define HED 4096
#define HFD 2048

typedef __attribute__((ext_vector_type(8))) short bf16x8;
typedef __attribute__((ext_vector_type(4))) float f32x4;
typedef unsigned short u16;

__device__ __forceinline__ u16 f2b(float f) {
    union { float f; uint32_t i; } c; c.f = f;
    uint32_t r = c.i + 0x7FFF + ((c.i >> 16) & 1);   // RNE
    return (u16)(r >> 16);
}
__device__ __forceinline__ float b2f(u16 u) {
    union { uint32_t i; float f; } c; c.i = ((uint32_t)u) << 16; return c.f;
}

// bijective XCD-chunk swizzle (m204). fast axis = bn so each XCD chunk covers
// FEW A-tiles x MANY B-panels -> the streamed A operand is shared through the
// XCD's private L2 (r8: L2 FETCH 274->81 MB).
__device__ __forceinline__ void xcd_swz(int flat, int nwg, int nFast, int& f, int& s) {
    int xcd = flat & 7, rest = flat >> 3;
    int q = nwg >> 3, r = nwg & 7;
    int wg = (xcd < r ? xcd * (q + 1) : r * (q + 1) + (xcd - r) * q) + rest;
    f = wg % nFast; s = wg / nFast;
}

#define GLDS(g, l) __builtin_amdgcn_global_load_lds( \
    (const __attribute__((address_space(1))) void*)(g), \
    (__attribute__((address_space(3))) void*)(l), 16, 0, 0)

// ================= fused prep: cnt init + x split + all weight transposes =================
// blocks [0, 8192): x -> bf16 hi/lo split (one float4 per thread)
// blocks [8192, 8192+5248): transpose tiles, matrix selected by cumulative table:
//   m0 router W_r1 (R=DD,C=HRD, hi/lo split)  tiles 128
//   m1 W_m1 (DD,HED) 1024 | m2 W_l1 (DD,HED) 1024 | m3 W_m2 (HED,DD) 1024
//   m4 W_l2 (HED,DD) 1024 | m5 W_f1 (DD,HFD) 512  | m6 W_f2 (HFD,DD) 512
struct PrepA {
    const float4* x4; ushort4* xhi; ushort4* xlo;
    const float* s0; u16* d0h; u16* d0l;
    const float* s1; u16* d1;
    const float* s2; u16* d2;
    const float* s3; u16* d3;
    const float* s4; u16* d4;
    const float* s5; u16* d5;
    const float* s6; u16* d6;
    int* cnt;
};

__global__ __launch_bounds__(256) void k_prep(PrepA a) {
    __shared__ float s[64][65];
    int bid = blockIdx.x, tid = threadIdx.x;
    if (bid == 0 && tid < 2) a.cnt[tid] = 0;
    if (bid < 8192) {
        int i = bid * 256 + tid;
        float4 v = a.x4[i];
        ushort4 h, l;
        h.x = f2b(v.x); l.x = f2b(v.x - b2f(h.x));
        h.y = f2b(v.y); l.y = f2b(v.y - b2f(h.y));
        h.z = f2b(v.z); l.z = f2b(v.z - b2f(h.z));
        h.w = f2b(v.w); l.w = f2b(v.w - b2f(h.w));
        a.xhi[i] = h; a.xlo[i] = l;
        return;
    }
    int rel = bid - 8192;
    const float* src; u16* dst; u16* dstLo = nullptr; int R, C;
    if (rel < 128)        { src = a.s0; dst = a.d0h; dstLo = a.d0l; R = DD;  C = HRD; }
    else if (rel < 1152)  { rel -= 128;  src = a.s1; dst = a.d1; R = DD;  C = HED; }
    else if (rel < 2176)  { rel -= 1152; src = a.s2; dst = a.d2; R = DD;  C = HED; }
    else if (rel < 3200)  { rel -= 2176; src = a.s3; dst = a.d3; R = HED; C = DD; }
    else if (rel < 4224)  { rel -= 3200; src = a.s4; dst = a.d4; R = HED; C = DD; }
    else if (rel < 4736)  { rel -= 4224; src = a.s5; dst = a.d5; R = DD;  C = HFD; }
    else                  { rel -= 4736; src = a.s6; dst = a.d6; R = HFD; C = DD; }
    int tilesX = C >> 6;
    int c0 = (rel % tilesX) * 64, r0 = (rel / tilesX) * 64;
    int tx = tid & 63, ty = tid >> 6;
#pragma unroll
    for (int j = 0; j < 16; j++) { int r = ty + j * 4; s[r][tx] = src[(size_t)(r0 + r) * C + c0 + tx]; }
    __syncthreads();
    if (dstLo) {
#pragma unroll
        for (int j = 0; j < 16; j++) {
            int c = ty + j * 4;
            float v = s[tx][c];
            u16 h = f2b(v);
            dst[(size_t)(c0 + c) * R + r0 + tx] = h;
            dstLo[(size_t)(c0 + c) * R + r0 + tx] = f2b(v - b2f(h));
        }
    } else {
#pragma unroll
        for (int j = 0; j < 16; j++) {
            int c = ty + j * 4;
            dst[(size_t)(c0 + c) * R + r0 + tx] = f2b(s[tx][c]);
        }
    }
}

// ---------------- LDS tile staging: 128 rows x 64 bf16 (256-thread router) ----------------
__device__ __forceinline__ void stage_tile(const char* gRowBase, long rowStrideBytes,
                                           u16* s, int tid) {
    int wave = tid >> 6, lane = tid & 63;
#pragma unroll
    for (int is = 0; is < 4; ++is) {
        int c = wave * 4 + is;                 // 1KB chunk, wave-uniform
        int row = c * 8 + (lane >> 3);
        const char* g = gRowBase + (long)row * rowStrideBytes + (lane & 7) * 16;
        GLDS(g, (char*)s + c * 1024);
    }
}

// ---------------- router GEMM (128^2 tile, 2-phase dbuf) ----------------
__global__ __launch_bounds__(256) void k_router(const u16* __restrict__ Ah, const u16* __restrict__ Al,
                                                const u16* __restrict__ Bh, const u16* __restrict__ Bl,
                                                const float* __restrict__ bias, float* __restrict__ H) {
    __shared__ u16 sAh[2][128 * 64], sAl[2][128 * 64], sBh[2][128 * 64], sBl[2][128 * 64];
    int tid = threadIdx.x, lane = tid & 63, wave = tid >> 6;
    int flat = blockIdx.y * gridDim.x + blockIdx.x;
    int bm, bn;
    xcd_swz(flat, gridDim.x * gridDim.y, gridDim.y, bn, bm);   // bn fast
    f32x4 acc[4][4];
#pragma unroll
    for (int i = 0; i < 4; i++)
#pragma unroll
        for (int j = 0; j < 4; j++) acc[i][j] = (f32x4)0.f;
    int wm = (wave & 1) * 64, wn = (wave >> 1) * 64;
    const char* ahBase = (const char*)(Ah + (size_t)bm * 128 * DD);
    const char* alBase = (const char*)(Al + (size_t)bm * 128 * DD);
    const char* bhBase = (const char*)(Bh + (size_t)bn * 128 * DD);
    const char* blBase = (const char*)(Bl + (size_t)bn * 128 * DD);
    const int nk = DD / 64;
    stage_tile(ahBase, DD * 2, sAh[0], tid);
    stage_tile(alBase, DD * 2, sAl[0], tid);
    stage_tile(bhBase, DD * 2, sBh[0], tid);
    stage_tile(blBase, DD * 2, sBl[0], tid);
    asm volatile("s_waitcnt vmcnt(0)" ::: "memory");
    __builtin_amdgcn_s_barrier();
    int cur = 0;
    for (int it = 0; it < nk; ++it) {
        if (it + 1 < nk) {
            size_t ofs = (size_t)(it + 1) * 128;
            stage_tile(ahBase + ofs, DD * 2, sAh[cur ^ 1], tid);
            stage_tile(alBase + ofs, DD * 2, sAl[cur ^ 1], tid);
            stage_tile(bhBase + ofs, DD * 2, sBh[cur ^ 1], tid);
            stage_tile(blBase + ofs, DD * 2, sBl[cur ^ 1], tid);
        }
        const u16* pAh = sAh[cur]; const u16* pAl = sAl[cur];
        const u16* pBh = sBh[cur]; const u16* pBl = sBl[cur];
#pragma unroll
        for (int kk = 0; kk < 2; kk++) {
            int kofs = kk * 64 + (lane >> 4) * 16;
            bf16x8 vbh[4], vbl[4];
#pragma unroll
            for (int ni = 0; ni < 4; ni++) {
                int rB = (wn + ni * 16 + (lane & 15)) * 128 + kofs;
                vbh[ni] = *(const bf16x8*)((const char*)pBh + rB);
                vbl[ni] = *(const bf16x8*)((const char*)pBl + rB);
            }
#pragma unroll
            for (int mi = 0; mi < 4; mi++) {
                int rA = (wm + mi * 16 + (lane & 15)) * 128 + kofs;
                bf16x8 vah = *(const bf16x8*)((const char*)pAh + rA);
                bf16x8 val = *(const bf16x8*)((const char*)pAl + rA);
#pragma unroll
                for (int ni = 0; ni < 4; ni++) {
                    acc[mi][ni] = __builtin_amdgcn_mfma_f32_16x16x32_bf16(vah, vbh[ni], acc[mi][ni], 0, 0, 0);
                    acc[mi][ni] = __builtin_amdgcn_mfma_f32_16x16x32_bf16(vah, vbl[ni], acc[mi][ni], 0, 0, 0);
                    acc[mi][ni] = __builtin_amdgcn_mfma_f32_16x16x32_bf16(val, vbh[ni], acc[mi][ni], 0, 0, 0);
                }
            }
        }
        asm volatile("s_waitcnt vmcnt(0)" ::: "memory");
        __builtin_amdgcn_s_barrier();
        cur ^= 1;
    }
    int quad = lane >> 4, cl = lane & 15;
#pragma unroll
    for (int mi = 0; mi < 4; mi++)
#pragma unroll
        for (int r = 0; r < 4; r++) {
            int row = bm * 128 + wm + mi * 16 + quad * 4 + r;
#pragma unroll
            for (int ni = 0; ni < 4; ni++) {
                int col = bn * 128 + wn + ni * 16 + cl;
                float v = acc[mi][ni][r] + bias[col];
                H[(size_t)row * HRD + col] = fmaxf(v, 0.f);
            }
        }
}

// ---------------- router heads ----------------
__global__ __launch_bounds__(256) void k_heads(const float* __restrict__ H,
                                               const float* __restrict__ Wd, const float* __restrict__ bd,
                                               const float* __restrict__ Wm, const float* __restrict__ Wl,
                                               int* __restrict__ cnt, int* __restrict__ perm,
                                               float* __restrict__ wsc, int* __restrict__ eic) {
    int lane = threadIdx.x & 63, wave = threadIdx.x >> 6;
    int r = blockIdx.x * 4 + wave;
    const float4* h4 = (const float4*)(H + (size_t)r * HRD);
    float4 v0 = h4[lane * 2], v1 = h4[lane * 2 + 1];
    float hv[8] = {v0.x, v0.y, v0.z, v0.w, v1.x, v1.y, v1.z, v1.w};
    float a[10];
#pragma unroll
    for (int t = 0; t < 10; t++) a[t] = 0.f;
    int kbase = lane * 8;
#pragma unroll
    for (int j = 0; j < 8; j++) {
        int k = kbase + j;
        float h_ = hv[j];
        float2 wd = ((const float2*)Wd)[k];
        a[0] += h_ * wd.x; a[1] += h_ * wd.y;
        float4 wm = ((const float4*)Wm)[k];
        a[2] += h_ * wm.x; a[3] += h_ * wm.y; a[4] += h_ * wm.z; a[5] += h_ * wm.w;
        float4 wl = ((const float4*)Wl)[k];
        a[6] += h_ * wl.x; a[7] += h_ * wl.y; a[8] += h_ * wl.z; a[9] += h_ * wl.w;
    }
#pragma unroll
    for (int t = 0; t < 10; t++)
#pragma unroll
        for (int off = 32; off > 0; off >>= 1) a[t] += __shfl_down(a[t], off);
    if (lane == 0) {
        float d0 = a[0] + bd[0], d1 = a[1] + bd[1];
        int primary = (d1 > d0) ? 1 : 0;                       // first-max tie-break
        float w = 1.f / (1.f + expf(-fabsf(d0 - d1)));         // softmax weight of chosen
        int mi = 0; float mv = a[2];
        if (a[3] > mv) { mv = a[3]; mi = 1; }
        if (a[4] > mv) { mv = a[4]; mi = 2; }
        if (a[5] > mv) { mv = a[5]; mi = 3; }
        int li = 0; float lv = a[6];
        if (a[7] > lv) { lv = a[7]; li = 1; }
        if (a[8] > lv) { lv = a[8]; li = 2; }
        int pos;
        if (a[9] > lv) { lv = a[9]; li = 3; }
        if (primary == 0) pos = atomicAdd(&cnt[0], 1);
        else              pos = NB - 1 - atomicAdd(&cnt[1], 1);
        perm[pos] = r; wsc[pos] = w; eic[pos] = (primary == 0) ? mi : li;
    }
}

// ---------------- gather ----------------
__global__ __launch_bounds__(256) void k_gather(const float* __restrict__ x,
                                                const float* __restrict__ op_emb,
                                                const float* __restrict__ task_emb,
                                                const int* __restrict__ perm, const int* __restrict__ eic,
                                                const int* __restrict__ cnt, u16* __restrict__ xin) {
    int lane = threadIdx.x & 63, wave = threadIdx.x >> 6;
    int i = blockIdx.x * 4 + wave;
    int n0 = cnt[0];
    int r = perm[i];
    const float* emb = ((i >= n0) ? task_emb : op_emb) + (size_t)eic[i] * DD;
    const float4* x4 = (const float4*)(x + (size_t)r * DD);
    const float4* e4 = (const float4*)emb;
    ushort4* o4 = (ushort4*)(xin + (size_t)i * DD);
#pragma unroll
    for (int j = 0; j < 4; j++) {
        int idx = lane + j * 64;
        float4 xv = x4[idx], ev = e4[idx];
        ushort4 o;
        o.x = f2b(xv.x + ev.x); o.y = f2b(xv.y + ev.y);
        o.z = f2b(xv.z + ev.z); o.w = f2b(xv.w + ev.w);
        o4[idx] = o;
    }
}

// ======== 256^2-tile staggered 4-phase GEMM for L1 / F1 (r11 passing) ========
template <bool DUAL>
__global__ __launch_bounds__(512) void k_g256(
    const u16* __restrict__ A, const u16* __restrict__ B0w, const u16* __restrict__ B1w,
    const float* __restrict__ bias0, const float* __restrict__ bias1,
    u16* __restrict__ Out, int K, int N, const int* __restrict__ cnt) {
    __shared__ __align__(16) u16 sA[2][256 * 64];
    __shared__ __align__(16) u16 sB[2][256 * 64];
    const int tid = threadIdx.x, lane = tid & 63, wave = tid >> 6;
    int flat = blockIdx.y * gridDim.x + blockIdx.x;
    int t, bn;
    xcd_swz(flat, gridDim.x * gridDim.y, gridDim.y, bn, t);   // bn fast

    int tile = t, storeLo = 0, storeHi = 0x7fffffff;
    const u16* Bt = B0w; const float* bias = bias0;
    if constexpr (DUAL) {
        int n0 = cnt[0];
        int tb = n0 >> 8;
        bool isMath = (t <= tb) && (t < NB / 256);
        tile = isMath ? t : (t - 1);
        if (isMath) { storeLo = tile * 256; storeHi = n0 < storeLo + 256 ? n0 : storeLo + 256; }
        else        { storeHi = tile * 256 + 256; storeLo = n0 > tile * 256 ? n0 : tile * 256;
                      Bt = B1w; bias = bias1; }
        if (storeLo >= storeHi) return;   // block-uniform, before any barrier
    }

    f32x4 acc[8][4];
#pragma unroll
    for (int i = 0; i < 8; i++)
#pragma unroll
        for (int j = 0; j < 4; j++) acc[i][j] = (f32x4)0.f;

    const int wm = (wave & 1) * 128;
    const int wn = (wave >> 1) * 64;
    const int rl = lane & 15, q = lane >> 4, x7 = lane & 7;
    const int aRow = (wave & 1) * 64;
    const int bRow = (wave >> 1) * 32;

    const long stride = (long)K * 2;
    const char* aBase = (const char*)A + (size_t)tile * 256 * stride;
    const char* bBase = (const char*)Bt + (size_t)bn * 256 * stride;
    const long srcOfs = (long)((lane & 7) ^ (lane >> 3)) << 4;
    const int waveOfs = wave * 1024;
    const int l8 = lane >> 3;

    auto SH_A = [&](int h, int kt, int d) {
        long kofs = (long)kt * 128 + srcOfs;
#pragma unroll
        for (int i = 0; i < 2; i++) {
            int gr = wave * 8 + l8 + h * 64 + i * 128;
            GLDS(aBase + (long)gr * stride + kofs,
                 (char*)&sA[d][0] + h * 16384 + i * 8192 + waveOfs);
        }
    };
    auto SH_B = [&](int h, int kt, int d) {
        long kofs = (long)kt * 128 + srcOfs;
#pragma unroll
        for (int i = 0; i < 2; i++) {
            int rp = i * 64 + wave * 8 + l8;
            int gn = (rp & 31) + ((rp >> 5) << 6) + h * 32;
            GLDS(bBase + (long)gn * stride + kofs,
                 (char*)&sB[d][0] + h * 16384 + i * 8192 + waveOfs);
        }
    };

    const int nk = K >> 6;
    SH_A(0, 0, 0); SH_B(0, 0, 0); SH_B(1, 0, 0); SH_A(1, 0, 0);
    if (nk > 1) {
        SH_A(0, 1, 1); SH_B(0, 1, 1); SH_B(1, 1, 1);
        asm volatile("s_waitcnt vmcnt(6)" ::: "memory");
    } else {
        asm volatile("s_waitcnt vmcnt(0)" ::: "memory");
    }
    __builtin_amdgcn_s_barrier();

    bf16x8 va[4][2], vb0[2][2], vb1[2][2];
    for (int kt = 0; kt < nk; ++kt) {
        const int cur = kt & 1;
        const char* pA = (const char*)&sA[cur][0];
        const char* pB = (const char*)&sB[cur][0];
        // P0
#pragma unroll
        for (int f = 0; f < 4; f++)
#pragma unroll
            for (int kk = 0; kk < 2; kk++)
                va[f][kk] = *(const bf16x8*)(pA + (aRow + f * 16 + rl) * 128 + (((kk * 4 + q) ^ x7) << 4));
#pragma unroll
        for (int g = 0; g < 2; g++)
#pragma unroll
            for (int kk = 0; kk < 2; kk++)
                vb0[g][kk] = *(const bf16x8*)(pB + (bRow + g * 16 + rl) * 128 + (((kk * 4 + q) ^ x7) << 4));
        if (kt + 1 < nk) SH_A(1, kt + 1, cur ^ 1);
        __builtin_amdgcn_s_setprio(1);
#pragma unroll
        for (int f = 0; f < 4; f++)
#pragma unroll
            for (int g = 0; g < 2; g++)
#pragma unroll
                for (int kk = 0; kk < 2; kk++)
                    acc[f][g] = __builtin_amdgcn_mfma_f32_16x16x32_bf16(va[f][kk], vb0[g][kk], acc[f][g], 0, 0, 0);
        __builtin_amdgcn_s_setprio(0);
        asm volatile("" ::: "memory");
        __builtin_amdgcn_s_barrier();
        // P1
#pragma unroll
        for (int g = 0; g < 2; g++)
#pragma unroll
            for (int kk = 0; kk < 2; kk++)
                vb1[g][kk] = *(const bf16x8*)(pB + (bRow + 128 + g * 16 + rl) * 128 + (((kk * 4 + q) ^ x7) << 4));
        if (kt + 2 < nk) SH_B(0, kt + 2, cur);
        __builtin_amdgcn_s_setprio(1);
#pragma unroll
        for (int f = 0; f < 4; f++)
#pragma unroll
            for (int g = 0; g < 2; g++)
#pragma unroll
                for (int kk = 0; kk < 2; kk++)
                    acc[f][2 + g] = __builtin_amdgcn_mfma_f32_16x16x32_bf16(va[f][kk], vb1[g][kk], acc[f][2 + g], 0, 0, 0);
        __builtin_amdgcn_s_setprio(0);
        asm volatile("" ::: "memory");
        __builtin_amdgcn_s_barrier();
        // P2
#pragma unroll
        for (int f = 0; f < 4; f++)
#pragma unroll
            for (int kk = 0; kk < 2; kk++)
                va[f][kk] = *(const bf16x8*)(pA + (aRow + 128 + f * 16 + rl) * 128 + (((kk * 4 + q) ^ x7) << 4));
        if (kt + 2 < nk) SH_B(1, kt + 2, cur);
        __builtin_amdgcn_s_setprio(1);
#pragma unroll
        for (int f = 0; f < 4; f++)
#pragma unroll
            for (int g = 0; g < 2; g++)
#pragma unroll
                for (int kk = 0; kk < 2; kk++)
                    acc[4 + f][2 + g] = __builtin_amdgcn_mfma_f32_16x16x32_bf16(va[f][kk], vb1[g][kk], acc[4 + f][2 + g], 0, 0, 0);
        __builtin_amdgcn_s_setprio(0);
        asm volatile("" ::: "memory");
        __builtin_amdgcn_s_barrier();
        // P3
        if (kt + 2 < nk) {
            SH_A(0, kt + 2, cur);
            asm volatile("s_waitcnt vmcnt(6)" ::: "memory");
        } else {
            asm volatile("s_waitcnt vmcnt(0)" ::: "memory");
        }
        __builtin_amdgcn_s_setprio(1);
#pragma unroll
        for (int f = 0; f < 4; f++)
#pragma unroll
            for (int g = 0; g < 2; g++)
#pragma unroll
                for (int kk = 0; kk < 2; kk++)
                    acc[4 + f][g] = __builtin_amdgcn_mfma_f32_16x16x32_bf16(va[f][kk], vb0[g][kk], acc[4 + f][g], 0, 0, 0);
        __builtin_amdgcn_s_setprio(0);
        asm volatile("" ::: "memory");
        __builtin_amdgcn_s_barrier();
    }

    const int quad = lane >> 4, cl = lane & 15;
#pragma unroll
    for (int f = 0; f < 8; f++)
#pragma unroll
        for (int rr = 0; rr < 4; rr++) {
            int grow = tile * 256 + wm + ((f & 3) * 16) + ((f >> 2) * 64) + quad * 4 + rr;
            if constexpr (DUAL) { if (grow < storeLo || grow >= storeHi) continue; }
#pragma unroll
            for (int g = 0; g < 4; g++) {
                int col = bn * 256 + wn + ((g & 1) * 16) + ((g >> 1) * 32) + cl;
                float v = acc[f][g][rr] + bias[col];
                Out[(size_t)grow * N + col] = f2b(fmaxf(v, 0.f));
            }
        }
}

// ======== 128^2-tile pipelined GEMM for L2 / F2 (r11 passing, 139us) ========
template <int EPI, bool DUAL>
__global__ __launch_bounds__(512) void k_gemm8p(
    const u16* __restrict__ A, const u16* __restrict__ B0, const u16* __restrict__ B1,
    const float* __restrict__ bias0, const float* __restrict__ bias1,
    void* __restrict__ Out, int K, int N,
    const int* __restrict__ cnt, const float* __restrict__ wsel,
    const int* __restrict__ perm, const u16* __restrict__ resid) {
    __shared__ __align__(16) u16 sA[2][128 * 64];
    __shared__ __align__(16) u16 sB[2][128 * 64];
    const int tid = threadIdx.x, lane = tid & 63, wave = tid >> 6;
    int flat = blockIdx.y * gridDim.x + blockIdx.x;
    int t, bn;
    xcd_swz(flat, gridDim.x * gridDim.y, gridDim.y, bn, t);   // bn fast

    int n0 = 0, tile = t, storeLo = 0, storeHi = 0x7fffffff;
    const u16* Bt = B0; const float* bias = bias0;
    if constexpr (DUAL) {
        n0 = cnt[0];
        int tb = n0 >> 7;
        bool isMath = (t <= tb) && (t < 64);
        tile = isMath ? t : (t - 1);
        if (isMath) { storeLo = tile * 128; storeHi = n0 < storeLo + 128 ? n0 : storeLo + 128; }
        else        { storeHi = tile * 128 + 128; storeLo = n0 > tile * 128 ? n0 : tile * 128;
                      Bt = B1; bias = bias1; }
        if (storeLo >= storeHi) return;   // block-uniform, before any barrier
    }

    f32x4 acc[4][2];
#pragma unroll
    for (int i = 0; i < 4; i++)
#pragma unroll
        for (int j = 0; j < 2; j++) acc[i][j] = (f32x4)0.f;

    const int wm = (wave & 1) * 64;
    const int wn = (wave >> 1) * 32;
    const int rl = lane & 15, q = lane >> 4, x7 = lane & 7;

    const long stride = (long)K * 2;
    const char* aBase = (const char*)A + (size_t)tile * 128 * stride;
    const char* bBase = (const char*)Bt + (size_t)bn * 128 * stride;
    const int rowInUnit = tid >> 3;
    const long srcOfs = (long)((tid & 7) ^ (rowInUnit & 7)) << 4;
    const int ldsWaveOfs = wave * 1024;

    auto STAGE = [&](int kt, int d) {
        long kofs = (long)kt * 128 + srcOfs;
#pragma unroll
        for (int i = 0; i < 2; i++)
            GLDS(aBase + (long)(i * 64 + rowInUnit) * stride + kofs,
                 (char*)&sA[d][0] + i * 8192 + ldsWaveOfs);
#pragma unroll
        for (int i = 0; i < 2; i++)
            GLDS(bBase + (long)(i * 64 + rowInUnit) * stride + kofs,
                 (char*)&sB[d][0] + i * 8192 + ldsWaveOfs);
    };

    STAGE(0, 0);
    const int nk = K >> 6;
    for (int k = 0; k < nk; ++k) {
        const int r_ = k & 1;
        if (k + 1 < nk) {
            STAGE(k + 1, r_ ^ 1);
            asm volatile("s_waitcnt vmcnt(4)" ::: "memory");
        } else {
            asm volatile("s_waitcnt vmcnt(0)" ::: "memory");
        }
        __builtin_amdgcn_s_barrier();
        const char* pA = (const char*)&sA[r_][0];
        const char* pB = (const char*)&sB[r_][0];
        bf16x8 vaA[2][2], vaB[2][2], vb0[2], vb1[2];
#pragma unroll
        for (int f = 0; f < 2; f++)
#pragma unroll
            for (int kk = 0; kk < 2; kk++)
                vaA[f][kk] = *(const bf16x8*)(pA + (wm + f * 16 + rl) * 128 + (((kk * 4 + q) ^ x7) << 4));
#pragma unroll
        for (int kk = 0; kk < 2; kk++)
            vb0[kk] = *(const bf16x8*)(pB + (wn + rl) * 128 + (((kk * 4 + q) ^ x7) << 4));
        __builtin_amdgcn_s_setprio(1);
#pragma unroll
        for (int f = 0; f < 2; f++)
#pragma unroll
            for (int kk = 0; kk < 2; kk++)
                acc[f][0] = __builtin_amdgcn_mfma_f32_16x16x32_bf16(vaA[f][kk], vb0[kk], acc[f][0], 0, 0, 0);
        __builtin_amdgcn_s_setprio(0);
#pragma unroll
        for (int kk = 0; kk < 2; kk++)
            vb1[kk] = *(const bf16x8*)(pB + (wn + 16 + rl) * 128 + (((kk * 4 + q) ^ x7) << 4));
        __builtin_amdgcn_s_setprio(1);
#pragma unroll
        for (int f = 0; f < 2; f++)
#pragma unroll
            for (int kk = 0; kk < 2; kk++)
                acc[f][1] = __builtin_amdgcn_mfma_f32_16x16x32_bf16(vaA[f][kk], vb1[kk], acc[f][1], 0, 0, 0);
        __builtin_amdgcn_s_setprio(0);
#pragma unroll
        for (int f = 0; f < 2; f++)
#pragma unroll
            for (int kk = 0; kk < 2; kk++)
                vaB[f][kk] = *(const bf16x8*)(pA + (wm + 32 + f * 16 + rl) * 128 + (((kk * 4 + q) ^ x7) << 4));
        __builtin_amdgcn_s_setprio(1);
#pragma unroll
        for (int f = 0; f < 2; f++)
#pragma unroll
            for (int kk = 0; kk < 2; kk++)
                acc[2 + f][1] = __builtin_amdgcn_mfma_f32_16x16x32_bf16(vaB[f][kk], vb1[kk], acc[2 + f][1], 0, 0, 0);
        __builtin_amdgcn_s_setprio(0);
        __builtin_amdgcn_s_setprio(1);
#pragma unroll
        for (int f = 0; f < 2; f++)
#pragma unroll
            for (int kk = 0; kk < 2; kk++)
                acc[2 + f][0] = __builtin_amdgcn_mfma_f32_16x16x32_bf16(vaB[f][kk], vb0[kk], acc[2 + f][0], 0, 0, 0);
        __builtin_amdgcn_s_setprio(0);
        asm volatile("" ::: "memory");
        __builtin_amdgcn_s_barrier();
    }

    const int quad = lane >> 4, cl = lane & 15;
#pragma unroll
    for (int mi = 0; mi < 4; mi++)
#pragma unroll
        for (int r = 0; r < 4; r++) {
            int grow = tile * 128 + wm + mi * 16 + quad * 4 + r;
            if constexpr (DUAL) { if (grow < storeLo || grow >= storeHi) continue; }
#pragma unroll
            for (int ni = 0; ni < 2; ni++) {
                int col = bn * 128 + wn + ni * 16 + cl;
                float v = acc[mi][ni][r] + bias[col];
                if constexpr (EPI == 0) {
                    ((u16*)Out)[(size_t)grow * N + col] = f2b(fmaxf(v, 0.f));
                } else if constexpr (EPI == 1) {
                    ((u16*)Out)[(size_t)grow * N + col] = f2b(v * wsel[grow]);
                } else {
                    v += b2f(resid[(size_t)grow * N + col]);
                    ((float*)Out)[(size_t)perm[grow] * N + col] = v;
                }
            }
        }
}

extern "C" void kernel_launch(void* const* d_in, const int* in_sizes, int n_in,
                              void* d_out, int out_size, void* d_ws, size_t ws_size,
                              hipStream_t stream) {
    const float* x      = (const float*)d_in[0];
    const float* W_r1   = (const float*)d_in[1];
    const float* b_r1   = (const float*)d_in[2];
    const float* W_dom  = (const float*)d_in[3];
    const float* b_dom  = (const float*)d_in[4];
    const float* W_mop  = (const float*)d_in[5];
    const float* W_lt   = (const float*)d_in[6];
    const float* op_emb = (const float*)d_in[7];
    const float* W_m1   = (const float*)d_in[8];
    const float* b_m1   = (const float*)d_in[9];
    const float* W_m2   = (const float*)d_in[10];
    const float* b_m2   = (const float*)d_in[11];
    const float* task_emb = (const float*)d_in[12];
    const float* W_l1   = (const float*)d_in[13];
    const float* b_l1   = (const float*)d_in[14];
    const float* W_l2   = (const float*)d_in[15];
    const float* b_l2   = (const float*)d_in[16];
    const float* W_f1   = (const float*)d_in[17];
    const float* b_f1   = (const float*)d_in[18];
    const float* W_f2   = (const float*)d_in[19];
    const float* b_f2   = (const float*)d_in[20];

    char* wsp = (char*)d_ws;
    size_t off = 0;
    auto take = [&](size_t bytes) -> char* {
        char* p = wsp + off;
        off += (bytes + 255) & ~(size_t)255;
        return p;
    };
    u16* Wr_hi = (u16*)take((size_t)HRD * DD * 2);
    u16* Wr_lo = (u16*)take((size_t)HRD * DD * 2);
    u16* Wm1t  = (u16*)take((size_t)HED * DD * 2);
    u16* Wl1t  = (u16*)take((size_t)HED * DD * 2);
    u16* Wm2t  = (u16*)take((size_t)DD * HED * 2);
    u16* Wl2t  = (u16*)take((size_t)DD * HED * 2);
    u16* Wf1t  = (u16*)take((size_t)HFD * DD * 2);
    u16* Wf2t  = (u16*)take((size_t)DD * HFD * 2);
    u16* x_hi  = (u16*)take((size_t)NB * DD * 2);
    u16* x_lo  = (u16*)take((size_t)NB * DD * 2);
    float* Hbuf = (float*)take((size_t)NB * HRD * 4);
    u16* hid   = (u16*)take((size_t)NB * HED * 2);
    int* cnt   = (int*)take(256);
    int* perm  = (int*)take(NB * 4);
    int* eic   = (int*)take(NB * 4);
    float* wsc = (float*)take(NB * 4);
    // aliases (lifetime-disjoint):
    u16* xin   = x_hi;   // gather runs after router GEMM consumed x_hi
    u16* fused = x_lo;   // L2 writes after router GEMM consumed x_lo
    u16* hid2  = Wm1t;   // F1 writes after all expert GEMMs consumed Wm1t..Wl2t (32MB contiguous)

    PrepA pa;
    pa.x4 = (const float4*)x; pa.xhi = (ushort4*)x_hi; pa.xlo = (ushort4*)x_lo;
    pa.s0 = W_r1; pa.d0h = Wr_hi; pa.d0l = Wr_lo;
    pa.s1 = W_m1; pa.d1 = Wm1t;
    pa.s2 = W_l1; pa.d2 = Wl1t;
    pa.s3 = W_m2; pa.d3 = Wm2t;
    pa.s4 = W_l2; pa.d4 = Wl2t;
    pa.s5 = W_f1; pa.d5 = Wf1t;
    pa.s6 = W_f2; pa.d6 = Wf2t;
    pa.cnt = cnt;
    k_prep<<<8192 + 5248, 256, 0, stream>>>(pa);

    k_router<<<dim3(NB / 128, HRD / 128), 256, 0, stream>>>(x_hi, x_lo, Wr_hi, Wr_lo, b_r1, Hbuf);
    k_heads<<<NB / 4, 256, 0, stream>>>(Hbuf, W_dom, b_dom, W_mop, W_lt, cnt, perm, wsc, eic);
    k_gather<<<NB / 4, 256, 0, stream>>>(x, op_emb, task_emb, perm, eic, cnt, xin);

    // L1: 256^2-tile staggered 4-phase, grid (33,16)=528 blocks
    k_g256<true><<<dim3(NB / 256 + 1, HED / 256), 512, 0, stream>>>(
        xin, Wm1t, Wl1t, b_m1, b_l1, hid, DD, HED, cnt);
    // L2: 128^2-tile pipelined (r11 passing, 139 us)
    k_gemm8p<1, true><<<dim3(NB / 128 + 1, DD / 128), 512, 0, stream>>>(
        hid, Wm2t, Wl2t, b_m2, b_l2, fused, HED, DD, cnt, wsc, nullptr, nullptr);
    // F1: 256^2-tile staggered 4-phase, grid (32,8)=256 blocks
    k_g256<false><<<dim3(NB / 256, HFD / 256), 512, 0, stream>>>(
        fused, Wf1t, nullptr, b_f1, nullptr, hid2, DD, HFD, cnt);
    // F2: 128^2-tile pipelined (r11 passing)
    k_gemm8p<2, false><<<dim3(NB / 128, DD / 128), 512, 0, stream>>>(
        hid2, Wf2t, nullptr, b_f2, nullptr, d_out, HFD, DD, cnt, nullptr, perm, fused);
}